// Round 18
// baseline (102.345 us; speedup 1.0000x reference)
//
#include <hip/hip_runtime.h>
#include <hip/hip_bf16.h>
#include <math.h>

#define N_NODES 20000
#define N_EDGES 200000
#define D_H 32
#define E_DIM 16
#define CAP 40                          // padded slots per node (max degree bound)
#define NPB 16                          // nodes per layer-block
#define LGRID (N_NODES / NPB)           // 1250 layer blocks
#define MSLOTS 384                      // max edges per block (Poisson(160), 17-sigma headroom)
#define MROW 36                         // padded msg row (shorts): 72B, 8B-aligned, bank-spread
#define W2S_SHORTS (17 * 2 * 64 * 8)    // 17408 bf16 (16x16 layout, R14-proven)
#define PREP_SHORTS (W2S_SHORTS + 512)  // + w1/b1 A-fragment = 17920
#define XPAIRS (N_NODES * 16)
#define EAPAIRS (N_EDGES * 8)
#define IB2 1563                        // init grid (400128 threads)

typedef __attribute__((ext_vector_type(8))) short bf16x8;
typedef __attribute__((ext_vector_type(4))) float f32x4;

__device__ __forceinline__ float elu_f(float v) { return v > 0.f ? v : expm1f(v); }
__device__ __forceinline__ short f2bf(float f) {
    union { __hip_bfloat16 h; short s; } u;
    u.h = __float2bfloat16(f);
    return u.s;
}
__device__ __forceinline__ float bfbits2f(short s) {
    union { __hip_bfloat16 h; short s; } u;
    u.s = s;
    return __bfloat162float(u.h);
}
__device__ __forceinline__ unsigned pack2(float lo, float hi) {
    return (unsigned)(unsigned short)f2bf(lo) | ((unsigned)(unsigned short)f2bf(hi) << 16);
}

// ---------------- init: zero cnt + 16x16 weight fragments + bf16 pre-conversion ----------------
__global__ __launch_bounds__(256)
void init_kernel(const float* __restrict__ w2_0, const float* __restrict__ b2_0,
                 const float* __restrict__ w1_0, const float* __restrict__ b1_0,
                 const float* __restrict__ w2_1, const float* __restrict__ b2_1,
                 const float* __restrict__ w1_1, const float* __restrict__ b1_1,
                 const float* __restrict__ x, const float* __restrict__ ea,
                 int* __restrict__ cnt, short* __restrict__ prep,
                 unsigned* __restrict__ xbf, unsigned* __restrict__ eabf)
{
    const int gid = blockIdx.x * 256 + threadIdx.x;
    const int nth = IB2 * 256;
    if (gid < N_NODES) cnt[gid] = 0;
    if (gid < 2 * PREP_SHORTS) {
        int layer = gid >= PREP_SHORTS ? 1 : 0;
        int r = gid - layer * PREP_SHORTS;
        const float* w2 = layer ? w2_1 : w2_0;
        const float* b2 = layer ? b2_1 : b2_0;
        const float* w1 = layer ? w1_1 : w1_0;
        const float* b1 = layer ? b1_1 : b1_0;
        float v;
        if (r < W2S_SHORTS) {
            int j = r & 7, l = (r >> 3) & 63, ct = (r >> 9) & 1, kk = r >> 10;
            int ii = (l >> 4) * 8 + j;
            int o = ct * 16 + (l & 15);
            v = (kk < 16) ? w2[kk * 1024 + ii * 32 + o] : b2[ii * 32 + o];
        } else {
            int q = r - W2S_SHORTS;
            int j = q & 7, l = q >> 3;
            int m = l & 15, k = (l >> 4) * 8 + j;
            v = (k < 16) ? w1[k * 16 + m] : (k == 16 ? b1[m] : 0.f);
        }
        prep[gid] = f2bf(v);
    }
    for (int i = gid; i < XPAIRS; i += nth) {
        const float2 p = *(const float2*)(x + (size_t)i * 2);
        xbf[i] = pack2(p.x, p.y);
    }
    for (int i = gid; i < EAPAIRS; i += nth) {
        const float2 p = *(const float2*)(ea + (size_t)i * 2);
        eabf[i] = pack2(p.x, p.y);
    }
}

// ---------------- fill: bucket edge ids by destination (padded), cnt becomes degree ----------------
__global__ __launch_bounds__(256)
void fill_kernel(const int* __restrict__ dst, int* __restrict__ cnt, int* __restrict__ elist) {
    int e = blockIdx.x * 256 + threadIdx.x;
    if (e < N_EDGES) {
        int d = dst[e];
        int r = atomicAdd(&cnt[d], 1);
        elist[d * CAP + r] = e;
    }
}

// ---------------- fused layer kernel: edge MFMA -> private LDS msg rows -> node phase ----------------
// Block: 512 thr (8 waves) owns NPB=16 dst nodes. NO atomics (R15 lesson):
// each edge's message goes to its own compacted LDS slot; node phase sums contiguous rows.
template<bool LAST>
__global__ __launch_bounds__(512)
void layer_kernel(const short* __restrict__ xin,       // [N,32] bf16
                  const short* __restrict__ eabf,      // [E,16] bf16
                  const int* __restrict__ src,
                  const int* __restrict__ elist,       // [N*CAP]
                  const int* __restrict__ cnt,         // [N] degrees
                  const short* __restrict__ prepL,
                  const float* __restrict__ root,
                  const float* __restrict__ bias,
                  const float* __restrict__ cls_w,
                  const float* __restrict__ cls_b,
                  __hip_bfloat16* __restrict__ hout,
                  float* __restrict__ out)
{
    __shared__ __align__(16) short w2s[PREP_SHORTS];       // 35840 B
    __shared__ __align__(8) short msg_s[MSLOTS + 1][MROW]; // 27720 B (+1 scratch row)
    __shared__ float root_s[1024];                         // 4096 B
    __shared__ float bias_s[32];
    __shared__ int list[MSLOTS];                           // 1536 B
    __shared__ int off_s[NPB + 1];
    __shared__ float h2_s[LAST ? NPB : 1][33];

    const int t = threadIdx.x;
    const int nb = blockIdx.x * NPB;

    for (int i = t; i < PREP_SHORTS / 8; i += 512)
        ((int4*)w2s)[i] = ((const int4*)prepL)[i];
    for (int i = t; i < 1024; i += 512) root_s[i] = root[i];
    if (t < 32) bias_s[t] = bias[t];
    if (t < NPB) off_s[t + 1] = cnt[nb + t];
    if (t == 0) off_s[0] = 0;
    __syncthreads();
    if (t == 0) {
        #pragma unroll
        for (int i = 1; i <= NPB; ++i) off_s[i] += off_s[i - 1];
    }
    __syncthreads();

    // compaction: 16 groups of 32 threads, one node each
    {
        const int ln = t >> 5;
        const int j0 = t & 31;
        const int base = off_s[ln];
        const int deg = off_s[ln + 1] - base;
        for (int j = j0; j < deg; j += 32)
            list[base + j] = elist[(nb + ln) * CAP + j];
    }
    __syncthreads();

    const int lane = t & 63;
    const int wave = t >> 6;
    const int eloc = lane & 15;
    const int kg = lane >> 4;
    const int total = off_s[NPB];
    const int ntiles = (total + 15) >> 4;
    const f32x4 zero4 = {0.f, 0.f, 0.f, 0.f};
    const bf16x8 w1f = *(const bf16x8*)&w2s[W2S_SHORTS + lane * 8];

    // -------- edge phase: R14-proven 16-edge-per-wave core, LDS store --------
    for (int tile = wave; tile < ntiles; tile += 8) {
        const int slot = tile * 16 + eloc;
        const bool valid = slot < total;
        const int e = valid ? list[slot] : list[0];
        const int row = valid ? slot : MSLOTS;   // dummies land in scratch row

        const int sn = src[e];
        const bf16x8 xf0 = *(const bf16x8*)(xin + (size_t)sn * 32 + kg * 8);

        bf16x8 ea0 = {0, 0, 0, 0, 0, 0, 0, 0};
        if (kg < 2) {
            ea0 = *(const bf16x8*)(eabf + (size_t)e * E_DIM + kg * 8);
        } else if (kg == 2) {
            ea0[0] = f2bf(1.0f);
        }

        // h-MFMA (swapped): lane holds h[k_out=(lane>>4)*4+r][edge=lane&15]
        f32x4 hd0 = __builtin_amdgcn_mfma_f32_16x16x32_bf16(w1f, ea0, zero4, 0, 0, 0);
        float hv0[4];
        #pragma unroll
        for (int r = 0; r < 4; ++r) hv0[r] = elu_f(hd0[r]);

        float m00[4] = {0, 0, 0, 0}, m01[4] = {0, 0, 0, 0};
        #pragma unroll
        for (int kk = 0; kk < 17; ++kk) {
            bf16x8 a0 = *(const bf16x8*)&w2s[(kk * 2 + 0) * 512 + lane * 8];
            bf16x8 a1 = *(const bf16x8*)&w2s[(kk * 2 + 1) * 512 + lane * 8];
            float h0;
            if (kk < 16) {
                h0 = __shfl(hv0[kk & 3], (kk >> 2) * 16 + eloc);
            } else {
                h0 = 1.0f;   // b2 K-step
            }
            f32x4 d00 = __builtin_amdgcn_mfma_f32_16x16x32_bf16(a0, xf0, zero4, 0, 0, 0);
            f32x4 d01 = __builtin_amdgcn_mfma_f32_16x16x32_bf16(a1, xf0, zero4, 0, 0, 0);
            #pragma unroll
            for (int r = 0; r < 4; ++r) {
                m00[r] += h0 * d00[r];
                m01[r] += h0 * d01[r];
            }
        }

        // store to private LDS row (no contention: one writer per (row, col-range))
        short q00[4] = { f2bf(m00[0]), f2bf(m00[1]), f2bf(m00[2]), f2bf(m00[3]) };
        short q01[4] = { f2bf(m01[0]), f2bf(m01[1]), f2bf(m01[2]), f2bf(m01[3]) };
        *(int2*)&msg_s[row][kg * 4]      = *(int2*)q00;
        *(int2*)&msg_s[row][16 + kg * 4] = *(int2*)q01;
    }
    __syncthreads();

    // -------- node phase: half-wave per node, contiguous LDS rows --------
    {
        const int half = lane >> 5;
        const int o = lane & 31;
        const int ln = wave * 2 + half;
        const int n = nb + ln;
        const int jb = off_s[ln], je = off_s[ln + 1];

        float s0 = 0.f, s1 = 0.f;
        int j = jb;
        for (; j + 1 < je; j += 2) {
            s0 += bfbits2f(msg_s[j][o]);
            s1 += bfbits2f(msg_s[j + 1][o]);
        }
        if (j < je) s0 += bfbits2f(msg_s[j][o]);

        float acc = (s0 + s1) * (1.f / fmaxf((float)(je - jb), 1.f)) + bias_s[o];
        const float xv = bfbits2f(xin[(size_t)n * 32 + o]);
        #pragma unroll
        for (int i = 0; i < 32; ++i)
            acc += __shfl(xv, half * 32 + i) * root_s[i * 32 + o];
        acc = elu_f(acc);

        if (!LAST) {
            hout[(size_t)n * 32 + o] = __float2bfloat16(acc);
        } else {
            h2_s[ln][o] = acc;
        }
    }
    if (LAST) {
        __syncthreads();
        if (t < NPB * 8) {
            const int nn = t >> 3, jj = t & 7;
            float a = cls_b[jj];
            #pragma unroll
            for (int i = 0; i < 32; ++i) a += h2_s[nn][i] * cls_w[i * 8 + jj];
            out[(size_t)(nb + nn) * 8 + jj] = a;
        }
    }
}

extern "C" void kernel_launch(void* const* d_in, const int* in_sizes, int n_in,
                              void* d_out, int out_size, void* d_ws, size_t ws_size,
                              hipStream_t stream)
{
    const float* x          = (const float*)d_in[0];
    const float* edge_attr  = (const float*)d_in[1];
    const int*   edge_index = (const int*)d_in[2];
    const float* w1_0 = (const float*)d_in[3];
    const float* b1_0 = (const float*)d_in[4];
    const float* w2_0 = (const float*)d_in[5];
    const float* b2_0 = (const float*)d_in[6];
    const float* root_0 = (const float*)d_in[7];
    const float* bias_0 = (const float*)d_in[8];
    const float* w1_1 = (const float*)d_in[9];
    const float* b1_1 = (const float*)d_in[10];
    const float* w2_1 = (const float*)d_in[11];
    const float* b2_1 = (const float*)d_in[12];
    const float* root_1 = (const float*)d_in[13];
    const float* bias_1 = (const float*)d_in[14];
    const float* cls_w = (const float*)d_in[15];
    const float* cls_b = (const float*)d_in[16];

    const int* src = edge_index;
    const int* dst = edge_index + N_EDGES;

    const int EB = (N_EDGES + 255) / 256;   // 782

    // ---- workspace layout (~12.4 MB) ----
    size_t off = 0;
    int* cnt = (int*)((char*)d_ws + off);            off += (size_t)N_NODES * 4;
    int* elist = (int*)((char*)d_ws + off);          off += (size_t)N_NODES * CAP * 4;
    off = (off + 15) & ~(size_t)15;
    short* prep = (short*)((char*)d_ws + off);       off += (size_t)2 * PREP_SHORTS * 2;
    off = (off + 15) & ~(size_t)15;
    unsigned* xbf = (unsigned*)((char*)d_ws + off);  off += (size_t)N_NODES * 32 * 2;
    off = (off + 15) & ~(size_t)15;
    unsigned* eabf = (unsigned*)((char*)d_ws + off); off += (size_t)N_EDGES * 16 * 2;
    off = (off + 15) & ~(size_t)15;
    __hip_bfloat16* hbuf = (__hip_bfloat16*)((char*)d_ws + off);

    // 4-dispatch fused pipeline (no atomics in layer kernels)
    init_kernel<<<IB2, 256, 0, stream>>>(w2_0, b2_0, w1_0, b1_0,
                                         w2_1, b2_1, w1_1, b1_1,
                                         x, edge_attr, cnt, prep, xbf, eabf);
    fill_kernel<<<EB, 256, 0, stream>>>(dst, cnt, elist);
    layer_kernel<false><<<LGRID, 512, 0, stream>>>((const short*)xbf, (const short*)eabf,
                                                   src, elist, cnt, prep,
                                                   root_0, bias_0, nullptr, nullptr,
                                                   hbuf, nullptr);
    layer_kernel<true><<<LGRID, 512, 0, stream>>>((const short*)hbuf, (const short*)eabf,
                                                  src, elist, cnt, prep + PREP_SHORTS,
                                                  root_1, bias_1, cls_w, cls_b,
                                                  nullptr, (float*)d_out);
}

// Round 19
// 79.830 us; speedup vs baseline: 1.2820x; 1.2820x over previous
//
#include <hip/hip_runtime.h>
#include <hip/hip_bf16.h>
#include <math.h>

#define N_NODES 20000
#define N_EDGES 200000
#define D_H 32
#define E_DIM 16
#define CAP 40                          // padded slots per node (max degree bound)
#define NJOBS1 (N_EDGES / 16)           // 12500 wave-jobs (16 edges each)
#define GBASE1 ((NJOBS1 + 7) / 8)       // 1563 edge blocks (512 thr, 8 waves)
#define ABASE (N_NODES / 4)             // 5000 agg blocks
#define W2S_SHORTS (17 * 2 * 64 * 8)    // 17408 bf16
#define PREP_SHORTS (W2S_SHORTS + 512)  // + w1/b1 A-fragment = 17920
#define XPAIRS (N_NODES * 16)           // 320000 float2->bf16x2 conversions
#define EAPAIRS (N_EDGES * 8)           // 1600000
#define IB2 1563                        // init grid (400128 threads)

typedef __attribute__((ext_vector_type(8))) short bf16x8;
typedef __attribute__((ext_vector_type(4))) float f32x4;

__device__ __forceinline__ float elu_f(float v) { return v > 0.f ? v : expm1f(v); }
__device__ __forceinline__ short f2bf(float f) {
    union { __hip_bfloat16 h; short s; } u;
    u.h = __float2bfloat16(f);
    return u.s;
}
__device__ __forceinline__ float bf2f(__hip_bfloat16 h) { return __bfloat162float(h); }
__device__ __forceinline__ unsigned pack2(float lo, float hi) {
    return (unsigned)(unsigned short)f2bf(lo) | ((unsigned)(unsigned short)f2bf(hi) << 16);
}

// ---------------- init: zero cnt + weight fragments + bf16 pre-conversion of x, edge_attr ----------------
__global__ __launch_bounds__(256)
void init_kernel(const float* __restrict__ w2_0, const float* __restrict__ b2_0,
                 const float* __restrict__ w1_0, const float* __restrict__ b1_0,
                 const float* __restrict__ w2_1, const float* __restrict__ b2_1,
                 const float* __restrict__ w1_1, const float* __restrict__ b1_1,
                 const float* __restrict__ x, const float* __restrict__ ea,
                 int* __restrict__ cnt, short* __restrict__ prep,
                 unsigned* __restrict__ xbf, unsigned* __restrict__ eabf)
{
    const int gid = blockIdx.x * 256 + threadIdx.x;
    const int nth = IB2 * 256;
    if (gid < N_NODES) cnt[gid] = 0;
    if (gid < 2 * PREP_SHORTS) {
        int layer = gid >= PREP_SHORTS ? 1 : 0;
        int r = gid - layer * PREP_SHORTS;
        const float* w2 = layer ? w2_1 : w2_0;
        const float* b2 = layer ? b2_1 : b2_0;
        const float* w1 = layer ? w1_1 : w1_0;
        const float* b1 = layer ? b1_1 : b1_0;
        float v;
        if (r < W2S_SHORTS) {
            int j = r & 7, l = (r >> 3) & 63, ct = (r >> 9) & 1, kk = r >> 10;
            int ii = (l >> 4) * 8 + j;
            int o = ct * 16 + (l & 15);
            v = (kk < 16) ? w2[kk * 1024 + ii * 32 + o] : b2[ii * 32 + o];
        } else {
            int q = r - W2S_SHORTS;
            int j = q & 7, l = q >> 3;
            int m = l & 15, k = (l >> 4) * 8 + j;
            v = (k < 16) ? w1[k * 16 + m] : (k == 16 ? b1[m] : 0.f);
        }
        prep[gid] = f2bf(v);
    }
    for (int i = gid; i < XPAIRS; i += nth) {
        const float2 p = *(const float2*)(x + (size_t)i * 2);
        xbf[i] = pack2(p.x, p.y);
    }
    for (int i = gid; i < EAPAIRS; i += nth) {
        const float2 p = *(const float2*)(ea + (size_t)i * 2);
        eabf[i] = pack2(p.x, p.y);
    }
}

// ---------------- CSR fallback helpers ----------------
__global__ __launch_bounds__(256)
void hist_kernel(const int* __restrict__ dst, int* __restrict__ cnt, int* __restrict__ ord) {
    int e = blockIdx.x * 256 + threadIdx.x;
    if (e < N_EDGES) ord[e] = atomicAdd(&cnt[dst[e]], 1);
}

__global__ __launch_bounds__(1024)
void scan_kernel(const int* __restrict__ cnt, int* __restrict__ rowptr) {
    __shared__ int part[1024];
    const int t = threadIdx.x;
    const int base = t * 20;
    int loc[20];
    int sum = 0;
    #pragma unroll
    for (int j = 0; j < 20; ++j) {
        int idx = base + j;
        int v = (idx < N_NODES) ? cnt[idx] : 0;
        loc[j] = v;
        sum += v;
    }
    part[t] = sum;
    __syncthreads();
    for (int off = 1; off < 1024; off <<= 1) {
        int v = (t >= off) ? part[t - off] : 0;
        __syncthreads();
        part[t] += v;
        __syncthreads();
    }
    int run = part[t] - sum;
    #pragma unroll
    for (int j = 0; j < 20; ++j) {
        int idx = base + j;
        if (idx < N_NODES) { rowptr[idx] = run; run += loc[j]; }
    }
    if (t == 0) rowptr[N_NODES] = N_EDGES;
}

// ---------------- fused edge kernel: 512-thr blocks, 1 tile (16 edges) per wave ----------------
// Lean per-wave state (~50 regs incl MFMA acc) for >=4 waves/SIMD occupancy (R14-proven).
// MODE 0: inline atomic rank (layer 0), saves pe.  MODE 1: pe from pebuf.  MODE 2: CSR fallback.
template<int MODE>
__global__ __launch_bounds__(512)
void edge_kernel(const short* __restrict__ xbf,        // [N,32] bf16
                 const short* __restrict__ eabf,       // [E,16] bf16
                 const int* __restrict__ src,
                 const int* __restrict__ dst,
                 int* __restrict__ cnt,          // MODE 0
                 int* __restrict__ pebuf,        // MODE 0 write, MODE 1 read
                 const int* __restrict__ ord,    // MODE 2
                 const int* __restrict__ rowptr, // MODE 2
                 const short* __restrict__ prepL,
                 __hip_bfloat16* __restrict__ msg)
{
    __shared__ __align__(16) short w2s[PREP_SHORTS];   // 35840 B

    const int t = threadIdx.x;
    for (int i = t; i < PREP_SHORTS / 8; i += 512)
        ((int4*)w2s)[i] = ((const int4*)prepL)[i];
    __syncthreads();

    const int lane = t & 63;
    const int wave = t >> 6;
    const int job = blockIdx.x * 8 + wave;
    if (job >= NJOBS1) return;
    const int eloc = lane & 15;
    const int kg = lane >> 4;

    const int e0 = job * 16 + eloc;

    int pe0;
    if (MODE == 0) {
        int p0_ = 0;
        if (kg == 0) {
            const int d0 = dst[e0];
            p0_ = d0 * CAP + atomicAdd(&cnt[d0], 1);
            pebuf[e0] = p0_;
        }
        pe0 = __shfl(p0_, eloc);
    } else if (MODE == 1) {
        pe0 = pebuf[e0];
    } else {
        pe0 = rowptr[dst[e0]] + ord[e0];
    }

    const int sn0 = src[e0];

    // x B-frag: single 16B bf16 load
    bf16x8 xf0 = *(const bf16x8*)(xbf + (size_t)sn0 * 32 + kg * 8);

    // edge-attr B-frag: bf16 direct; k==16 -> 1.0 (bias), else 0
    bf16x8 ea0 = {0,0,0,0,0,0,0,0};
    if (kg < 2) {
        ea0 = *(const bf16x8*)(eabf + (size_t)e0 * E_DIM + kg * 8);
    } else if (kg == 2) {
        ea0[0] = f2bf(1.0f);
    }

    const f32x4 zero4 = {0.f, 0.f, 0.f, 0.f};

    // h-MFMA (swapped): lane holds h[k_out=(lane>>4)*4+r][edge=lane&15]
    bf16x8 w1f = *(const bf16x8*)&w2s[W2S_SHORTS + lane * 8];
    f32x4 hd0 = __builtin_amdgcn_mfma_f32_16x16x32_bf16(w1f, ea0, zero4, 0, 0, 0);
    float hv0[4];
    #pragma unroll
    for (int r = 0; r < 4; ++r) hv0[r] = elu_f(hd0[r]);

    float m00[4]={0,0,0,0}, m01[4]={0,0,0,0};
    #pragma unroll
    for (int kk = 0; kk < 17; ++kk) {
        bf16x8 a0 = *(const bf16x8*)&w2s[(kk * 2 + 0) * 512 + lane * 8];
        bf16x8 a1 = *(const bf16x8*)&w2s[(kk * 2 + 1) * 512 + lane * 8];
        float h0;
        if (kk < 16) {
            h0 = __shfl(hv0[kk & 3], (kk >> 2) * 16 + eloc);
        } else {
            h0 = 1.0f;   // b2 K-step
        }
        f32x4 d00 = __builtin_amdgcn_mfma_f32_16x16x32_bf16(a0, xf0, zero4, 0, 0, 0);
        f32x4 d01 = __builtin_amdgcn_mfma_f32_16x16x32_bf16(a1, xf0, zero4, 0, 0, 0);
        #pragma unroll
        for (int r = 0; r < 4; ++r) {
            m00[r] += h0 * d00[r];
            m01[r] += h0 * d01[r];
        }
    }

    short* mp0 = (short*)(msg + (size_t)pe0 * D_H);
    short q00[4] = { f2bf(m00[0]), f2bf(m00[1]), f2bf(m00[2]), f2bf(m00[3]) };
    short q01[4] = { f2bf(m01[0]), f2bf(m01[1]), f2bf(m01[2]), f2bf(m01[3]) };
    *(int2*)(mp0 + kg * 4)      = *(int2*)q00;
    *(int2*)(mp0 + 16 + kg * 4) = *(int2*)q01;
}

// ---------------- aggregation (R8-proven): wave/node, halves split rows, 4-deep prefetch ----------------
template<bool LAST, bool PADDED>
__global__ __launch_bounds__(256)
void agg_kernel(const void* __restrict__ xin_,          // f32 x (layer0) or bf16 hbuf (layer1)
                const __hip_bfloat16* __restrict__ msg,
                const int* __restrict__ rowptr,   // CSR
                const int* __restrict__ cnt,      // PADDED
                const float* __restrict__ root,
                const float* __restrict__ bias,
                const float* __restrict__ cls_w,
                const float* __restrict__ cls_b,
                __hip_bfloat16* __restrict__ hout,
                float* __restrict__ out)
{
    __shared__ float root_s[32 * 32];
    __shared__ float bias_s[32];
    __shared__ float h2_s[4][33];
    const int t = threadIdx.x;
    for (int i = t; i < 1024; i += 256) root_s[i] = root[i];
    if (t < 32) bias_s[t] = bias[t];
    __syncthreads();

    const int lane = t & 63;
    const int wave = t >> 6;
    const int o = lane & 31;
    const int half = lane >> 5;
    const int n = blockIdx.x * 4 + wave;

    int start, end;
    if (PADDED) { start = n * CAP; end = start + cnt[n]; }
    else        { start = rowptr[n]; end = rowptr[n + 1]; }

    float s = 0.f;
    int j = start + half;
    for (; j + 6 < end; j += 8) {
        float v0 = bf2f(msg[(size_t)(j    ) * D_H + o]);
        float v1 = bf2f(msg[(size_t)(j + 2) * D_H + o]);
        float v2 = bf2f(msg[(size_t)(j + 4) * D_H + o]);
        float v3 = bf2f(msg[(size_t)(j + 6) * D_H + o]);
        s += (v0 + v1) + (v2 + v3);
    }
    for (; j < end; j += 2)
        s += bf2f(msg[(size_t)j * D_H + o]);
    s += __shfl_xor(s, 32);

    float acc = s * (1.f / fmaxf((float)(end - start), 1.f)) + bias_s[o];
    const float xv = LAST ? bf2f(((const __hip_bfloat16*)xin_)[(size_t)n * 32 + o])
                          : ((const float*)xin_)[(size_t)n * 32 + o];
    #pragma unroll
    for (int i = 0; i < 32; ++i)
        acc += __shfl(xv, half * 32 + i) * root_s[i * 32 + o];
    acc = elu_f(acc);

    if (!LAST) {
        if (half == 0) hout[(size_t)n * 32 + o] = __float2bfloat16(acc);
    } else {
        if (half == 0) h2_s[wave][o] = acc;
        __syncthreads();
        if (t < 32) {
            const int nn = t >> 3, jj = t & 7;
            float a = cls_b[jj];
            #pragma unroll
            for (int i = 0; i < 32; ++i) a += h2_s[nn][i] * cls_w[i * 8 + jj];
            out[(size_t)(blockIdx.x * 4 + nn) * 8 + jj] = a;
        }
    }
}

extern "C" void kernel_launch(void* const* d_in, const int* in_sizes, int n_in,
                              void* d_out, int out_size, void* d_ws, size_t ws_size,
                              hipStream_t stream)
{
    const float* x          = (const float*)d_in[0];
    const float* edge_attr  = (const float*)d_in[1];
    const int*   edge_index = (const int*)d_in[2];
    const float* w1_0 = (const float*)d_in[3];
    const float* b1_0 = (const float*)d_in[4];
    const float* w2_0 = (const float*)d_in[5];
    const float* b2_0 = (const float*)d_in[6];
    const float* root_0 = (const float*)d_in[7];
    const float* bias_0 = (const float*)d_in[8];
    const float* w1_1 = (const float*)d_in[9];
    const float* b1_1 = (const float*)d_in[10];
    const float* w2_1 = (const float*)d_in[11];
    const float* b2_1 = (const float*)d_in[12];
    const float* root_1 = (const float*)d_in[13];
    const float* bias_1 = (const float*)d_in[14];
    const float* cls_w = (const float*)d_in[15];
    const float* cls_b = (const float*)d_in[16];

    const int* src = edge_index;
    const int* dst = edge_index + N_EDGES;

    const int EB = (N_EDGES + 255) / 256;   // 782

    // ---- padded-path workspace layout ----
    size_t need = 0;
    size_t o_cnt = need;  need += (size_t)N_NODES * 4;
    size_t o_pe  = need;  need += (size_t)N_EDGES * 4;
    size_t o_prep= (need + 15) & ~(size_t)15; need = o_prep + (size_t)2 * PREP_SHORTS * 2;
    size_t o_xbf = (need + 15) & ~(size_t)15; need = o_xbf + (size_t)N_NODES * 32 * 2;
    size_t o_ea  = (need + 15) & ~(size_t)15; need = o_ea  + (size_t)N_EDGES * 16 * 2;
    size_t o_msg = (need + 63) & ~(size_t)63; need = o_msg + (size_t)N_NODES * CAP * D_H * 2;
    size_t o_hb  = (need + 15) & ~(size_t)15; need = o_hb + (size_t)N_NODES * D_H * 2;

    char* ws = (char*)d_ws;

    if (ws_size >= need) {
        // ======== 5-dispatch padded path (R14/R16-proven, 80.2 us) ========
        int* cnt = (int*)(ws + o_cnt);
        int* pe  = (int*)(ws + o_pe);
        short* prep = (short*)(ws + o_prep);
        unsigned* xbf  = (unsigned*)(ws + o_xbf);
        unsigned* eabf = (unsigned*)(ws + o_ea);
        __hip_bfloat16* msg  = (__hip_bfloat16*)(ws + o_msg);
        __hip_bfloat16* hbuf = (__hip_bfloat16*)(ws + o_hb);

        init_kernel<<<IB2, 256, 0, stream>>>(w2_0, b2_0, w1_0, b1_0,
                                             w2_1, b2_1, w1_1, b1_1,
                                             x, edge_attr, cnt, prep, xbf, eabf);
        edge_kernel<0><<<GBASE1, 512, 0, stream>>>((const short*)xbf, (const short*)eabf,
                                                   src, dst, cnt, pe, nullptr, nullptr,
                                                   prep, msg);
        agg_kernel<false, true><<<ABASE, 256, 0, stream>>>(x, msg, nullptr, cnt,
                                                           root_0, bias_0, nullptr, nullptr,
                                                           hbuf, nullptr);
        edge_kernel<1><<<GBASE1, 512, 0, stream>>>((const short*)hbuf, (const short*)eabf,
                                                   src, dst, nullptr, pe, nullptr, nullptr,
                                                   prep + PREP_SHORTS, msg);
        agg_kernel<true, true><<<ABASE, 256, 0, stream>>>(hbuf, msg, nullptr, cnt,
                                                          root_1, bias_1, cls_w, cls_b,
                                                          nullptr, (float*)d_out);
    } else {
        // ======== 7-dispatch CSR fallback ========
        size_t f = 0;
        int* cnt    = (int*)ws;                 f += (size_t)N_NODES * 4;
        int* rowptr = (int*)(ws + f);           f += (size_t)(N_NODES + 1) * 4;
        int* ord    = (int*)(ws + f);           f += (size_t)N_EDGES * 4;
        f = (f + 15) & ~(size_t)15;
        short* prep = (short*)(ws + f);         f += (size_t)2 * PREP_SHORTS * 2;
        f = (f + 15) & ~(size_t)15;
        unsigned* xbf = (unsigned*)(ws + f);    f += (size_t)N_NODES * 32 * 2;
        f = (f + 15) & ~(size_t)15;
        unsigned* eabf = (unsigned*)(ws + f);   f += (size_t)N_EDGES * 16 * 2;
        f = (f + 63) & ~(size_t)63;
        __hip_bfloat16* msg = (__hip_bfloat16*)(ws + f); f += (size_t)N_EDGES * D_H * 2;
        f = (f + 15) & ~(size_t)15;
        __hip_bfloat16* hbuf = (__hip_bfloat16*)(ws + f);

        init_kernel<<<IB2, 256, 0, stream>>>(w2_0, b2_0, w1_0, b1_0,
                                             w2_1, b2_1, w1_1, b1_1,
                                             x, edge_attr, cnt, prep, xbf, eabf);
        hist_kernel<<<EB, 256, 0, stream>>>(dst, cnt, ord);
        scan_kernel<<<1, 1024, 0, stream>>>(cnt, rowptr);

        edge_kernel<2><<<GBASE1, 512, 0, stream>>>((const short*)xbf, (const short*)eabf,
                                                   src, dst, nullptr, nullptr, ord, rowptr,
                                                   prep, msg);
        agg_kernel<false, false><<<ABASE, 256, 0, stream>>>(x, msg, rowptr, nullptr,
                                                            root_0, bias_0, nullptr, nullptr,
                                                            hbuf, nullptr);
        edge_kernel<2><<<GBASE1, 512, 0, stream>>>((const short*)hbuf, (const short*)eabf,
                                                   src, dst, nullptr, nullptr, ord, rowptr,
                                                   prep + PREP_SHORTS, msg);
        agg_kernel<true, false><<<ABASE, 256, 0, stream>>>(hbuf, msg, rowptr, nullptr,
                                                           root_1, bias_1, cls_w, cls_b,
                                                           nullptr, (float*)d_out);
    }
}